// Round 8
// baseline (158.444 us; speedup 1.0000x reference)
//
#include <hip/hip_runtime.h>
#include <cmath>

// Problem constants (fixed by reference)
constexpr int Dd = 1024;   // embed dim
constexpr int Bn = 64;     // n_image == n_caption
constexpr int Sr = 36;     // regions
constexpr int Lm = 32;     // max caption length
constexpr float SMOOTH = 9.0f;
constexpr float LLSE   = 6.0f;
constexpr float EPSF   = 1e-8f;

using frag_ab = __attribute__((ext_vector_type(8))) short;  // 8 bf16 (4 VGPRs)
using frag_cd = __attribute__((ext_vector_type(4))) float;  // 4 fp32 acc

__device__ inline short f2bf(float f) {            // RNE fp32 -> bf16
  union { float f; unsigned u; } v{f};
  unsigned r = v.u + 0x7FFF + ((v.u >> 16) & 1);
  return (short)(r >> 16);
}
__device__ inline float bf2f(short h) {
  union { unsigned u; float f; } v;
  v.u = ((unsigned)(unsigned short)h) << 16;
  return v.f;
}

__device__ inline void gload16(const short* g, short* l) {
  // async global->LDS, 16B/lane; LDS dest = wave-uniform base + lane*16
  __builtin_amdgcn_global_load_lds(
      (__attribute__((address_space(1))) void*)g,
      (__attribute__((address_space(3))) void*)l, 16, 0, 0);
}

// ---------------------------------------------------------------------------
// Fused prep: blockIdx ranges
//   [0, 3328)    : fp32->bf16 conversion of images (2304 blk) + W_g (1024 blk)
//   [3328, 5376) : captions conversion fused with per-row l2 norm (w1)
//   [5376, 7680) : Gram rows, one block per (b, s)
// ---------------------------------------------------------------------------
__global__ __launch_bounds__(256) void prep_kernel(
    const float* __restrict__ images, short* __restrict__ imgbf,
    const float* __restrict__ W_g, short* __restrict__ Wbf,
    const float* __restrict__ captions, short* __restrict__ capbf,
    float* __restrict__ w1, float* __restrict__ G)
{
  const int blk = blockIdx.x;
  const int tid = threadIdx.x;
  __shared__ float4 ref[256];
  __shared__ float wsum[4];

  if (blk < 3328) {
    int i = blk * 1024 + tid * 4;
    const float* src; short* dst;
    if (i < 2304 * 1024) { src = images + i; dst = imgbf + i; }
    else { int j = i - 2304 * 1024; src = W_g + j; dst = Wbf + j; }
    float4 v = *(const float4*)src;
    short4 o;
    o.x = f2bf(v.x); o.y = f2bf(v.y); o.z = f2bf(v.z); o.w = f2bf(v.w);
    *(short4*)dst = o;
  } else if (blk < 5376) {
    const int r = blk - 3328;           // caption row 0..2047
    float4 v = *(const float4*)(captions + (size_t)r * Dd + tid * 4);
    short4 o;
    o.x = f2bf(v.x); o.y = f2bf(v.y); o.z = f2bf(v.z); o.w = f2bf(v.w);
    *(short4*)(capbf + (size_t)r * Dd + tid * 4) = o;
    float s = v.x * v.x + v.y * v.y + v.z * v.z + v.w * v.w;
#pragma unroll
    for (int off = 32; off; off >>= 1) s += __shfl_xor(s, off);
    if ((tid & 63) == 0) wsum[tid >> 6] = s;
    __syncthreads();
    if (tid == 0) w1[r] = sqrtf(wsum[0] + wsum[1] + wsum[2] + wsum[3]);
  } else {
    const int p = blk - 5376;
    const int b = p / Sr, s = p % Sr;
    ref[tid] = ((const float4*)(images + (size_t)(b * Sr + s) * Dd))[tid];
    __syncthreads();
    const int wv = tid >> 6, lane = tid & 63;
    for (int s2 = wv; s2 < Sr; s2 += 4) {
      const float4* row2 = (const float4*)(images + (size_t)(b * Sr + s2) * Dd);
      float acc = 0.f;
#pragma unroll
      for (int j = 0; j < 4; j++) {
        float4 a = ref[lane + j * 64];
        float4 c = row2[lane + j * 64];
        acc += a.x * c.x + a.y * c.y + a.z * c.z + a.w * c.w;
      }
#pragma unroll
      for (int o = 32; o; o >>= 1) acc += __shfl_xor(acc, o);
      if (lane == 0) G[(size_t)b * Sr * Sr + s * Sr + s2] = acc;
    }
  }
}

// ---------------------------------------------------------------------------
// GEMM1 (E = cap @ W^T): 256-thr, 32x64 tile, BK=64, double-buffered,
// XOR-swizzled LDS.
// ---------------------------------------------------------------------------
template <int BM, int BN, int MINW>
__global__ __launch_bounds__(256, MINW) void mfma_gemm_dbuf(
    const short* __restrict__ A, const short* __restrict__ B,
    short* __restrict__ C, int K, int ldc)
{
  constexpr int FI = BM / 32;
  constexpr int FJ = BN / 32;
  __shared__ __align__(16) short LA[2][BM * 64];
  __shared__ __align__(16) short LB[2][BN * 64];

  const int t    = threadIdx.x;
  const int lane = t & 63;
  const int w    = t >> 6;
  const int wm   = w >> 1;
  const int wn   = w & 1;
  const int m0 = blockIdx.y * BM;
  const int n0 = blockIdx.x * BN;

  const int rIn = t >> 3;
  const int ch  = (t & 7) ^ (rIn & 7);
  const short* gA = A + (size_t)(m0 + rIn) * K + ch * 8;
  const short* gB = B + (size_t)(n0 + rIn) * K + ch * 8;

  const int fr = lane & 15;
  const int fq = lane >> 4;
  const int p0 = fq ^ (fr & 7);

  frag_cd acc[FI][FJ] = {};

  auto stage = [&](int buf, int k0) {
#pragma unroll
    for (int j = 0; j < BM / 32; j++)
      gload16(gA + (size_t)j * 32 * K + k0, &LA[buf][j * 2048 + w * 512]);
#pragma unroll
    for (int j = 0; j < BN / 32; j++)
      gload16(gB + (size_t)j * 32 * K + k0, &LB[buf][j * 2048 + w * 512]);
  };

  stage(0, 0);
  int cur = 0;
  for (int k0 = 0; k0 < K; k0 += 64) {
    __syncthreads();
    if (k0 + 64 < K) stage(cur ^ 1, k0 + 64);

    const short* aBase = &LA[cur][(wm * (FI * 16) + fr) * 64];
    const short* bBase = &LB[cur][(wn * (FJ * 16) + fr) * 64];
#pragma unroll
    for (int th = 0; th < 2; th++) {
      const int pa = p0 ^ (th * 4);
      frag_ab af[FI], bf[FJ];
#pragma unroll
      for (int i = 0; i < FI; i++)
        af[i] = *(const frag_ab*)(aBase + i * 16 * 64 + pa * 8);
#pragma unroll
      for (int j = 0; j < FJ; j++)
        bf[j] = *(const frag_ab*)(bBase + j * 16 * 64 + pa * 8);
#pragma unroll
      for (int i = 0; i < FI; i++)
#pragma unroll
        for (int j = 0; j < FJ; j++)
          acc[i][j] = __builtin_amdgcn_mfma_f32_16x16x32_bf16(
              af[i], bf[j], acc[i][j], 0, 0, 0);
    }
    cur ^= 1;
  }

#pragma unroll
  for (int i = 0; i < FI; i++) {
    int row = m0 + wm * (FI * 16) + i * 16 + fq * 4;
#pragma unroll
    for (int j = 0; j < FJ; j++) {
      int col = n0 + wn * (FJ * 16) + j * 16 + fr;
#pragma unroll
      for (int r = 0; r < 4; r++)
        C[(size_t)(row + r) * ldc + col] = f2bf(acc[i][j][r]);
    }
  }
}

// ---------------------------------------------------------------------------
// GEMM2 (Cbig = images @ Bcat^T): 128-thread / 2-wave blocks, block tile
// 128x64, WAVE tile 64x64 (m97-class LDS-B/FLOP), BK=64, single-buffer,
// XOR-swizzled LDS. 24.6 KB LDS -> 6 blocks/CU = 12 waves/CU.
// ---------------------------------------------------------------------------
__global__ __launch_bounds__(128, 3) void gemm2_w64(
    const short* __restrict__ A, const short* __restrict__ B,
    short* __restrict__ C, int K, int ldc)
{
  __shared__ __align__(16) short As[128 * 64];
  __shared__ __align__(16) short Bs[64 * 64];

  const int t    = threadIdx.x;     // 0..127
  const int lane = t & 63;
  const int w    = t >> 6;          // wave 0..1 (m-halves)
  const int m0 = blockIdx.y * 128;
  const int n0 = blockIdx.x * 64;

  const int rIn = t >> 3;
  const int ch  = (t & 7) ^ (rIn & 7);
  const short* gA = A + (size_t)(m0 + rIn) * K + ch * 8;
  const short* gB = B + (size_t)(n0 + rIn) * K + ch * 8;

  const int fr = lane & 15;
  const int fq = lane >> 4;
  const int p0 = fq ^ (fr & 7);

  frag_cd acc[4][4] = {};

  for (int k0 = 0; k0 < K; k0 += 64) {
    __syncthreads();                 // prev-iter LDS readers done
#pragma unroll
    for (int j = 0; j < 8; j++)      // A: 128 rows, 16 per issue
      gload16(gA + (size_t)j * 16 * K + k0, As + j * 1024 + w * 512);
#pragma unroll
    for (int j = 0; j < 4; j++)      // B: 64 rows
      gload16(gB + (size_t)j * 16 * K + k0, Bs + j * 1024 + w * 512);
    __syncthreads();                 // barrier drains vmcnt -> tile published

    const short* aBase = As + (w * 64 + fr) * 64;
    const short* bBase = Bs + fr * 64;
#pragma unroll
    for (int th = 0; th < 2; th++) {
      const int pa = p0 ^ (th * 4);  // swizzled chunk pos for this k-half
      frag_ab af[4], bf[4];
#pragma unroll
      for (int i = 0; i < 4; i++)
        af[i] = *(const frag_ab*)(aBase + i * 16 * 64 + pa * 8);
#pragma unroll
      for (int j = 0; j < 4; j++)
        bf[j] = *(const frag_ab*)(bBase + j * 16 * 64 + pa * 8);
#pragma unroll
      for (int i = 0; i < 4; i++)
#pragma unroll
        for (int j = 0; j < 4; j++)
          acc[i][j] = __builtin_amdgcn_mfma_f32_16x16x32_bf16(
              af[i], bf[j], acc[i][j], 0, 0, 0);
    }
  }

  // C/D layout: col = lane&15, row = (lane>>4)*4 + reg  [verified m89/m91]
#pragma unroll
  for (int i = 0; i < 4; i++) {
    int row = m0 + w * 64 + i * 16 + fq * 4;
#pragma unroll
    for (int j = 0; j < 4; j++) {
      int col = n0 + j * 16 + fr;
#pragma unroll
      for (int r = 0; r < 4; r++)
        C[(size_t)(row + r) * ldc + col] = f2bf(acc[i][j][r]);
    }
  }
}

// ---------------------------------------------------------------------------
// Finalize v3: block = (image b, 4 captions); one wave per (b,cap).
// R7's version spilled a_reg[36] to scratch (dynamic index s = s0*18+k) —
// VGPR_Count 52 / VALUBusy 0.66% / 135 µs. v3: ALL a_reg indices are
// compile-time constants (full 36-unroll, both halves redundantly compute
// the full w12/w2 sums — divergent half-loops would serialize anyway).
// Gram is read directly from global with wave-uniform addresses -> compiler
// emits s_load through the constant cache (no LDS pipe, no VGPR cost).
// No __syncthreads needed: all LDS arrays are per-wave slices.
// ---------------------------------------------------------------------------
__global__ __launch_bounds__(256) void finalize_kernel(
    const short* __restrict__ Cbig, const float* __restrict__ G,
    const float* __restrict__ w1arr, const int* __restrict__ lens,
    float* __restrict__ out)
{
  const int b    = blockIdx.x;       // image
  const int cg   = blockIdx.y;       // caption group of 4
  const int t    = threadIdx.x;
  const int wv   = t >> 6;           // wave -> caption within group
  const int lane = t & 63;
  const int cap  = cg * 4 + wv;
  const int l    = lane & 31;        // word
  const int s0   = lane >> 5;        // s-parity for load/norm phases

  __shared__ float att[4][Sr][Lm];   // per-wave working attn
  __shared__ short cims[4][Sr][Lm];  // per-wave bf16 cap.img dots

  const int len = lens[cap];

  // load + leaky-relu + mask (2 s-rows per step: s = 2k + s0)
#pragma unroll
  for (int k = 0; k < 18; k++) {
    int s = k * 2 + s0;
    size_t row = (size_t)(b * Sr + s) * 4096;
    float x = bf2f(Cbig[row + cap * Lm + l]);
    x = x > 0.f ? x : 0.1f * x;
    if (l >= len) x = 0.f;
    att[wv][s][l] = x;
    cims[wv][s][l] = Cbig[row + 2048 + cap * Lm + l];
  }

  // l2 norm over words l, per region s (width-32 shuffle reduce)
#pragma unroll
  for (int k = 0; k < 18; k++) {
    int s = k * 2 + s0;
    float v = att[wv][s][l];
    float ss = v * v;
#pragma unroll
    for (int o = 16; o; o >>= 1) ss += __shfl_xor(ss, o);
    att[wv][s][l] = v * (1.f / (sqrtf(ss) + EPSF));
  }

  // softmax over regions s, per word l (half 0 computes; same-wave visibility)
  if (s0 == 0) {
    float m = -1e30f;
#pragma unroll
    for (int s = 0; s < Sr; s++) m = fmaxf(m, att[wv][s][l]);
    m *= SMOOTH;
    float sum = 0.f;
#pragma unroll
    for (int s = 0; s < Sr; s++) {
      float e = expf(SMOOTH * att[wv][s][l] - m);
      att[wv][s][l] = e; sum += e;
    }
    float inv = 1.f / sum;
#pragma unroll
    for (int s = 0; s < Sr; s++) att[wv][s][l] *= inv;
  }

  // a into registers — constant indices only (no scratch)
  float a_reg[Sr];
#pragma unroll
  for (int s = 0; s < Sr; s++) a_reg[s] = att[wv][s][l];

  // w12 = a . cim ; w2^2 = a^T G a  (G via uniform scalar loads)
  const float* Grow = G + (size_t)b * Sr * Sr;
  float w12 = 0.f, w2 = 0.f;
#pragma unroll
  for (int s = 0; s < Sr; s++) {
    float a = a_reg[s];
    w12 += a * bf2f(cims[wv][s][l]);
    float tt = 0.f;
#pragma unroll
    for (int s2 = 0; s2 < Sr; s2++)
      tt += Grow[s * Sr + s2] * a_reg[s2];
    w2 += a * tt;
  }

  // cosine + LogSumExp over valid words (width-32; halves identical)
  float w1v = w1arr[cap * Lm + l];
  float denom = fmaxf(w1v * sqrtf(fmaxf(w2, 0.f)), EPSF);
  float rs = w12 / denom;
  float z = (l < len) ? rs * LLSE : -1e30f;
  float m = z;
#pragma unroll
  for (int o = 16; o; o >>= 1) m = fmaxf(m, __shfl_xor(m, o));
  float e = expf(z - m);
#pragma unroll
  for (int o = 16; o; o >>= 1) e += __shfl_xor(e, o);
  if (lane == 0) out[(size_t)b * Bn + cap] = (m + logf(e)) / LLSE;
}

// ---------------------------------------------------------------------------
extern "C" void kernel_launch(void* const* d_in, const int* in_sizes, int n_in,
                              void* d_out, int out_size, void* d_ws, size_t ws_size,
                              hipStream_t stream)
{
  const float* images   = (const float*)d_in[0];  // (64,36,1024)
  const float* captions = (const float*)d_in[1];  // (64,32,1024)
  const int*   cap_lens = (const int*)d_in[2];    // (64,)
  const float* W_g      = (const float*)d_in[3];  // (1024,1024)
  float* out = (float*)d_out;                     // (64,64)

  // Workspace (~34.4 MB):
  short* imgbf = (short*)d_ws;                          // 2304*1024 bf16
  short* Bcat  = imgbf + (size_t)2304 * 1024;           // 4096*1024 bf16: [0:2048)=E, [2048:4096)=captions
  short* capbf = Bcat + (size_t)2048 * 1024;
  short* Wbf   = Bcat + (size_t)4096 * 1024;            // 1024*1024 bf16
  short* Cbig  = Wbf + (size_t)1024 * 1024;             // 2304*4096 bf16
  float* Gram  = (float*)(Cbig + (size_t)2304 * 4096);  // 64*36*36 fp32
  float* w1a   = Gram + (size_t)Bn * Sr * Sr;           // 2048 fp32

  // conversions + w1 + gram fused (7680 blocks)
  prep_kernel<<<7680, 256, 0, stream>>>(
      images, imgbf, W_g, Wbf, captions, capbf, w1a, Gram);

  // E = captions @ W_g^T (2048x1024x1024), 32x64 tiles -> 1024 blocks
  mfma_gemm_dbuf<32, 64, 4><<<dim3(1024 / 64, 2048 / 32), 256, 0, stream>>>(
      capbf, Wbf, Bcat, Dd, 1024);
  // Cbig = images @ Bcat^T (2304x4096x1024): 128x64 blocks, 2 waves,
  // wave tile 64x64 -> 1152 blocks, 6 blocks/CU
  gemm2_w64<<<dim3(4096 / 64, 2304 / 128), 128, 0, stream>>>(
      imgbf, Bcat, Cbig, Dd, 4096);

  // finalize: block = image x 4 captions, one wave per (b,cap)
  finalize_kernel<<<dim3(Bn, Bn / 4), 256, 0, stream>>>(
      Cbig, Gram, w1a, cap_lens, out);
}